// Round 1
// 28242.459 us; speedup vs baseline: 1.3688x; 1.3688x over previous
//
#include <hip/hip_runtime.h>
#include <cstddef>
#include <cstdint>

// Problem: GRU  B=32, L=1024, D_IN=512, H=512
// inputs: x(32,1024,512) f32, init_states(32,512) f32,
//         W_ru(1024,1024) f32 [cols 0:512 = Wh_ru, 512:1024 = Wx_ru],
//         b_ru(1024), W_c(512,1024) [cols 0:512 = Wh_c, 512:1024 = Wx_c], b_c(512)
// outputs: outs(32,1024,512) then h_last(32,512), flat in d_out.

#define Bsz   32
#define Lsz   1024
#define Hsz   512
#define NG    1536   // 1024 ru gates + 512 cand

// recurrence decomposition
#define NBLK    256   // total blocks (co-resident, cooperative launch)
#define GROUPS  4     // batch groups
#define BPG     64    // blocks per group
#define BATG    8     // batches per group
#define JB      8     // h-columns owned per block
#define WSTR    513   // padded LDS row stride (odd -> conflict-free)
#define THREADS 256

__device__ __forceinline__ float sigmoidf_(float v) {
    return 1.0f / (1.0f + __expf(-v));
}
__device__ __forceinline__ float tanhf_(float v) {
    float e = __expf(2.0f * v);           // inf -> 1, 0 -> -1 : correct saturation
    return 1.0f - 2.0f / (e + 1.0f);
}
__device__ __forceinline__ float ld_agent(const float* p) {
    return __hip_atomic_load(p, __ATOMIC_RELAXED, __HIP_MEMORY_SCOPE_AGENT);
}
__device__ __forceinline__ void st_agent(float* p, float v) {
    __hip_atomic_store(p, v, __ATOMIC_RELAXED, __HIP_MEMORY_SCOPE_AGENT);
}

// Tree-reduce 8 per-lane partials across 32 lanes (lanes l..l^31 share one batch).
// On exit every lane holds, in a[0], the FULL k-sum for column jj = (l & 7).
__device__ __forceinline__ void reduce8(float a[8], int l) {
    #pragma unroll
    for (int i = 0; i < 4; ++i) {
        float lo = a[2 * i], hi = a[2 * i + 1];
        float ex = __shfl_xor((l & 1) ? lo : hi, 1);
        a[i] = (l & 1) ? (hi + ex) : (lo + ex);
    }
    #pragma unroll
    for (int i = 0; i < 2; ++i) {
        float lo = a[2 * i], hi = a[2 * i + 1];
        float ex = __shfl_xor((l & 2) ? lo : hi, 2);
        a[i] = (l & 2) ? (hi + ex) : (lo + ex);
    }
    {
        float lo = a[0], hi = a[1];
        float ex = __shfl_xor((l & 4) ? lo : hi, 4);
        a[0] = (l & 4) ? (hi + ex) : (lo + ex);
    }
    a[0] += __shfl_xor(a[0], 8);
    a[0] += __shfl_xor(a[0], 16);
}

__global__ __launch_bounds__(256) void init_h(const float* __restrict__ h0,
                                              float* __restrict__ hstate) {
    int i = blockIdx.x * 256 + threadIdx.x;
    hstate[i] = h0[i];
}

// ---------------- input-projection GEMM (unchanged, ~2% of runtime) --------
__global__ __launch_bounds__(256) void gemm_pre(const float* __restrict__ x,
                                                const float* __restrict__ W_ru,
                                                const float* __restrict__ b_ru,
                                                const float* __restrict__ W_c,
                                                const float* __restrict__ b_c,
                                                float* __restrict__ pre,
                                                int t0) {
    __shared__ float As[8][128];
    __shared__ float Bs[8][128];
    const int tid = threadIdx.x;
    const int bm = blockIdx.x, bn = blockIdx.y;
    const int tx = tid & 15, ty = tid >> 4;

    const int lrow = tid >> 1;
    const int lk4  = (tid & 1) * 4;
    const int grow = bm * 128 + lrow;          // row = t_local*32 + b
    const int tt = grow >> 5, bb = grow & 31;
    const float* xrow = x + ((size_t)bb * Lsz + (t0 + tt)) * 512;
    const int gn = bn * 128 + lrow;            // output column (gate index)
    const float* wrow = (gn < 1024) ? (W_ru + (size_t)gn * 1024 + 512)
                                    : (W_c  + (size_t)(gn - 1024) * 1024 + 512);

    float acc[8][8];
    #pragma unroll
    for (int i = 0; i < 8; ++i)
        #pragma unroll
        for (int j = 0; j < 8; ++j) acc[i][j] = 0.0f;

    for (int k0 = 0; k0 < 512; k0 += 8) {
        float4 av = *(const float4*)(xrow + k0 + lk4);
        float4 bv = *(const float4*)(wrow + k0 + lk4);
        __syncthreads();
        As[lk4 + 0][lrow] = av.x; As[lk4 + 1][lrow] = av.y;
        As[lk4 + 2][lrow] = av.z; As[lk4 + 3][lrow] = av.w;
        Bs[lk4 + 0][lrow] = bv.x; Bs[lk4 + 1][lrow] = bv.y;
        Bs[lk4 + 2][lrow] = bv.z; Bs[lk4 + 3][lrow] = bv.w;
        __syncthreads();
        #pragma unroll
        for (int k = 0; k < 8; ++k) {
            float a[8], b[8];
            *(float4*)&a[0] = *(const float4*)&As[k][ty * 8];
            *(float4*)&a[4] = *(const float4*)&As[k][ty * 8 + 4];
            *(float4*)&b[0] = *(const float4*)&Bs[k][tx * 8];
            *(float4*)&b[4] = *(const float4*)&Bs[k][tx * 8 + 4];
            #pragma unroll
            for (int i = 0; i < 8; ++i)
                #pragma unroll
                for (int j = 0; j < 8; ++j)
                    acc[i][j] += a[i] * b[j];
        }
    }

    const int row0 = bm * 128 + ty * 8;
    const int col0 = bn * 128 + tx * 8;
    float bias[8];
    #pragma unroll
    for (int j = 0; j < 8; ++j) {
        int c = col0 + j;
        bias[j] = (c < 1024) ? b_ru[c] : b_c[c - 1024];
    }
    #pragma unroll
    for (int i = 0; i < 8; ++i) {
        float4 v0 = make_float4(acc[i][0] + bias[0], acc[i][1] + bias[1],
                                acc[i][2] + bias[2], acc[i][3] + bias[3]);
        float4 v1 = make_float4(acc[i][4] + bias[4], acc[i][5] + bias[5],
                                acc[i][6] + bias[6], acc[i][7] + bias[7]);
        float* p = pre + (size_t)(row0 + i) * NG + col0;
        *(float4*)p = v0;
        *(float4*)(p + 4) = v1;
    }
}

// ---------------- persistent cooperative recurrence ------------------------
// 256 blocks x 256 threads.  group g = bid>>6 owns batches 8g..8g+7;
// slice s = bid&63 owns h-columns j0..j0+7 (its Wr/Wz/Wc rows live in LDS,
// loaded ONCE per launch).  thread (tid): batch = 8g + (tid>>5), lane l=tid&31
// covers k = kk*32 + l.  h and r*h cross blocks via agent-scope atomics;
// z / h_own stay in registers (column-aligned ownership).  Two per-group
// counter barriers per step.
__global__ __launch_bounds__(THREADS, 1) void gru_rec(
        const float* __restrict__ W_ru, const float* __restrict__ W_c,
        const float* __restrict__ pre, float* __restrict__ h_buf,
        float* __restrict__ rh_buf, unsigned* __restrict__ cnt,
        float* __restrict__ out, float* __restrict__ hlast,
        int t0, int Tc) {
    __shared__ float Wl[3 * JB * WSTR];      // 48.1 KB
    float* Wr_s = Wl;
    float* Wz_s = Wl + JB * WSTR;
    float* Wc_s = Wl + 2 * JB * WSTR;

    const int bid  = blockIdx.x;
    const int g    = bid >> 6;
    const int j0   = (bid & 63) * JB;
    const int tid  = threadIdx.x;
    const int b    = g * BATG + (tid >> 5);  // global batch for this thread
    const int l    = tid & 31;
    const int jown = l & 7;                  // column this lane finalizes
    unsigned* bar_cnt = cnt + g * 16;        // 64B-separated per group

    // one-time LDS fill: rows j0..j0+7 of Wh_r, Wh_z, Wh_c (k-contiguous)
    for (int idx = tid; idx < JB * 512; idx += THREADS) {
        int jj = idx >> 9, k = idx & 511;
        Wr_s[jj * WSTR + k] = W_ru[(size_t)(j0 + jj) * 1024 + k];
        Wz_s[jj * WSTR + k] = W_ru[(size_t)(512 + j0 + jj) * 1024 + k];
        Wc_s[jj * WSTR + k] = W_c [(size_t)(j0 + jj) * 1024 + k];
    }
    __syncthreads();

    float* hb = h_buf  + (size_t)b * Hsz;
    float* rb = rh_buf + (size_t)b * Hsz;
    unsigned bar = 0;

    for (int t = 0; t < Tc; ++t) {
        const float* prow = pre + ((size_t)t * Bsz + b) * NG;

        // ---- phase A: r,z gates for owned columns ----
        float hv[16];
        #pragma unroll
        for (int kk = 0; kk < 16; ++kk)
            hv[kk] = ld_agent(hb + kk * 32 + l);
        float h_own = ld_agent(hb + j0 + jown);

        float ar[8], az[8];
        #pragma unroll
        for (int jj = 0; jj < 8; ++jj) { ar[jj] = 0.f; az[jj] = 0.f; }
        #pragma unroll
        for (int kk = 0; kk < 16; ++kk) {
            const int k = kk * 32 + l;
            const float h = hv[kk];
            #pragma unroll
            for (int jj = 0; jj < 8; ++jj) {
                ar[jj] = fmaf(Wr_s[jj * WSTR + k], h, ar[jj]);
                az[jj] = fmaf(Wz_s[jj * WSTR + k], h, az[jj]);
            }
        }
        reduce8(ar, l);
        reduce8(az, l);

        float r = sigmoidf_(ar[0] + prow[j0 + jown]);
        float z = sigmoidf_(az[0] + prow[512 + j0 + jown]);
        if (l < 8) st_agent(rb + j0 + l, r * h_own);

        // ---- group barrier 1 (publish rh) ----
        ++bar;
        __syncthreads();   // drains vmcnt -> rh stores at coherence point
        if (tid == 0) {
            __hip_atomic_fetch_add(bar_cnt, 1u, __ATOMIC_RELEASE, __HIP_MEMORY_SCOPE_AGENT);
            while (__hip_atomic_load(bar_cnt, __ATOMIC_ACQUIRE, __HIP_MEMORY_SCOPE_AGENT)
                   < bar * BPG)
                __builtin_amdgcn_s_sleep(2);
        }
        __syncthreads();

        // ---- phase B: candidate + h update for owned columns ----
        float rv[16];
        #pragma unroll
        for (int kk = 0; kk < 16; ++kk)
            rv[kk] = ld_agent(rb + kk * 32 + l);

        float ac[8];
        #pragma unroll
        for (int jj = 0; jj < 8; ++jj) ac[jj] = 0.f;
        #pragma unroll
        for (int kk = 0; kk < 16; ++kk) {
            const int k = kk * 32 + l;
            const float p = rv[kk];
            #pragma unroll
            for (int jj = 0; jj < 8; ++jj)
                ac[jj] = fmaf(Wc_s[jj * WSTR + k], p, ac[jj]);
        }
        reduce8(ac, l);

        float c  = tanhf_(ac[0] + prow[1024 + j0 + jown]);
        float hn = h_own + z * (c - h_own);      // (1-z)h + z*c
        if (l < 8) {
            st_agent(hb + j0 + l, hn);
            out[((size_t)b * Lsz + (t0 + t)) * Hsz + j0 + l] = hn;
            if (t0 + t == Lsz - 1) hlast[(size_t)b * Hsz + j0 + l] = hn;
        }

        // ---- group barrier 2 (publish h, protect rh from next-step WAR) ----
        ++bar;
        __syncthreads();
        if (tid == 0) {
            __hip_atomic_fetch_add(bar_cnt, 1u, __ATOMIC_RELEASE, __HIP_MEMORY_SCOPE_AGENT);
            while (__hip_atomic_load(bar_cnt, __ATOMIC_ACQUIRE, __HIP_MEMORY_SCOPE_AGENT)
                   < bar * BPG)
                __builtin_amdgcn_s_sleep(2);
        }
        __syncthreads();
    }
}

// ---------------------------------------------------------------------------
extern "C" void kernel_launch(void* const* d_in, const int* in_sizes, int n_in,
                              void* d_out, int out_size, void* d_ws, size_t ws_size,
                              hipStream_t stream) {
    const float* x     = (const float*)d_in[0];
    const float* h0    = (const float*)d_in[1];
    const float* W_ru  = (const float*)d_in[2];
    const float* b_ru  = (const float*)d_in[3];
    const float* W_c   = (const float*)d_in[4];
    const float* b_c   = (const float*)d_in[5];
    float* out   = (float*)d_out;
    float* hlast = out + (size_t)Bsz * Lsz * Hsz;

    float* ws       = (float*)d_ws;
    unsigned* cnt   = (unsigned*)ws;            // 64 u32 (4 groups, 64B apart)
    float* h_buf    = ws + 64;                  // 32*512
    float* rh_buf   = h_buf + Bsz * Hsz;        // 32*512
    float* pre      = rh_buf + Bsz * Hsz;       // Tc*32*1536

    const size_t fixed_bytes = (size_t)(64 + 2 * Bsz * Hsz) * 4;
    int Tc = 256;
    while (Tc > 8 && fixed_bytes + (size_t)Tc * Bsz * NG * 4 > ws_size) Tc >>= 1;

    init_h<<<(Bsz * Hsz) / 256, 256, 0, stream>>>(h0, h_buf);

    const int nchunks = Lsz / Tc;
    for (int cidx = 0; cidx < nchunks; ++cidx) {
        int t0 = cidx * Tc;
        gemm_pre<<<dim3((Tc * Bsz) / 128, NG / 128), 256, 0, stream>>>(
            x, W_ru, b_ru, W_c, b_c, pre, t0);
        hipMemsetAsync(cnt, 0, 64 * sizeof(unsigned), stream);
        void* args[] = {(void*)&W_ru, (void*)&W_c, (void*)&pre, (void*)&h_buf,
                        (void*)&rh_buf, (void*)&cnt, (void*)&out, (void*)&hlast,
                        (void*)&t0, (void*)&Tc};
        hipLaunchCooperativeKernel(reinterpret_cast<void*>(gru_rec),
                                   dim3(NBLK), dim3(THREADS), args, 0u, stream);
    }
}

// Round 2
// 19226.152 us; speedup vs baseline: 2.0107x; 1.4690x over previous
//
#include <hip/hip_runtime.h>
#include <cstddef>
#include <cstdint>

// Problem: GRU  B=32, L=1024, D_IN=512, H=512
// inputs: x(32,1024,512) f32, init_states(32,512) f32,
//         W_ru(1024,1024) f32 [cols 0:512 = Wh_ru, 512:1024 = Wx_ru],
//         b_ru(1024), W_c(512,1024) [cols 0:512 = Wh_c, 512:1024 = Wx_c], b_c(512)
// outputs: outs(32,1024,512) then h_last(32,512), flat in d_out.

#define Bsz   32
#define Lsz   1024
#define Hsz   512
#define NG    1536   // 1024 ru gates + 512 cand

// recurrence decomposition
#define NBLK    256   // total blocks (co-resident, cooperative launch)
#define GROUPS  4     // batch groups
#define BPG     64    // blocks per group
#define BATG    8     // batches per group
#define JB      8     // h-columns owned per block
#define WSTR    513   // padded LDS row stride (odd -> conflict-free)
#define THREADS 256
#define FSTR    16    // flag stride in u32 (64B: one cache line per block, no RMW contention)

__device__ __forceinline__ float sigmoidf_(float v) {
    return 1.0f / (1.0f + __expf(-v));
}
__device__ __forceinline__ float tanhf_(float v) {
    float e = __expf(2.0f * v);           // inf -> 1, 0 -> -1 : correct saturation
    return 1.0f - 2.0f / (e + 1.0f);
}
__device__ __forceinline__ float ld_agent(const float* p) {
    return __hip_atomic_load(p, __ATOMIC_RELAXED, __HIP_MEMORY_SCOPE_AGENT);
}
__device__ __forceinline__ void st_agent(float* p, float v) {
    __hip_atomic_store(p, v, __ATOMIC_RELAXED, __HIP_MEMORY_SCOPE_AGENT);
}

// Flag-array group barrier: one release-store per block to its own 64B slot
// (stores to distinct lines pipeline -- no RMW serialization), then wave 0
// polls all BPG flags in one vector load per iteration.
__device__ __forceinline__ void group_barrier(unsigned* flags, int slice,
                                              int tid, unsigned bar) {
    __syncthreads();   // each wave drains vmcnt -> all data stores at coherence point
    if (tid == 0)
        __hip_atomic_store(&flags[(size_t)slice * FSTR], bar,
                           __ATOMIC_RELEASE, __HIP_MEMORY_SCOPE_AGENT);
    if (tid < BPG) {
        while (__hip_atomic_load(&flags[(size_t)tid * FSTR],
                                 __ATOMIC_ACQUIRE, __HIP_MEMORY_SCOPE_AGENT) < bar)
            __builtin_amdgcn_s_sleep(1);
    }
    __syncthreads();
}

// Tree-reduce 8 per-lane partials across 32 lanes (lanes l..l^31 share one batch).
// On exit every lane holds, in a[0], the FULL k-sum for column jj = (l & 7).
__device__ __forceinline__ void reduce8(float a[8], int l) {
    #pragma unroll
    for (int i = 0; i < 4; ++i) {
        float lo = a[2 * i], hi = a[2 * i + 1];
        float ex = __shfl_xor((l & 1) ? lo : hi, 1);
        a[i] = (l & 1) ? (hi + ex) : (lo + ex);
    }
    #pragma unroll
    for (int i = 0; i < 2; ++i) {
        float lo = a[2 * i], hi = a[2 * i + 1];
        float ex = __shfl_xor((l & 2) ? lo : hi, 2);
        a[i] = (l & 2) ? (hi + ex) : (lo + ex);
    }
    {
        float lo = a[0], hi = a[1];
        float ex = __shfl_xor((l & 4) ? lo : hi, 4);
        a[0] = (l & 4) ? (hi + ex) : (lo + ex);
    }
    a[0] += __shfl_xor(a[0], 8);
    a[0] += __shfl_xor(a[0], 16);
}

__global__ __launch_bounds__(256) void init_h(const float* __restrict__ h0,
                                              float* __restrict__ hstate) {
    int i = blockIdx.x * 256 + threadIdx.x;
    hstate[i] = h0[i];
}

// ---------------- input-projection GEMM (unchanged, ~2% of runtime) --------
__global__ __launch_bounds__(256) void gemm_pre(const float* __restrict__ x,
                                                const float* __restrict__ W_ru,
                                                const float* __restrict__ b_ru,
                                                const float* __restrict__ W_c,
                                                const float* __restrict__ b_c,
                                                float* __restrict__ pre,
                                                int t0) {
    __shared__ float As[8][128];
    __shared__ float Bs[8][128];
    const int tid = threadIdx.x;
    const int bm = blockIdx.x, bn = blockIdx.y;
    const int tx = tid & 15, ty = tid >> 4;

    const int lrow = tid >> 1;
    const int lk4  = (tid & 1) * 4;
    const int grow = bm * 128 + lrow;          // row = t_local*32 + b
    const int tt = grow >> 5, bb = grow & 31;
    const float* xrow = x + ((size_t)bb * Lsz + (t0 + tt)) * 512;
    const int gn = bn * 128 + lrow;            // output column (gate index)
    const float* wrow = (gn < 1024) ? (W_ru + (size_t)gn * 1024 + 512)
                                    : (W_c  + (size_t)(gn - 1024) * 1024 + 512);

    float acc[8][8];
    #pragma unroll
    for (int i = 0; i < 8; ++i)
        #pragma unroll
        for (int j = 0; j < 8; ++j) acc[i][j] = 0.0f;

    for (int k0 = 0; k0 < 512; k0 += 8) {
        float4 av = *(const float4*)(xrow + k0 + lk4);
        float4 bv = *(const float4*)(wrow + k0 + lk4);
        __syncthreads();
        As[lk4 + 0][lrow] = av.x; As[lk4 + 1][lrow] = av.y;
        As[lk4 + 2][lrow] = av.z; As[lk4 + 3][lrow] = av.w;
        Bs[lk4 + 0][lrow] = bv.x; Bs[lk4 + 1][lrow] = bv.y;
        Bs[lk4 + 2][lrow] = bv.z; Bs[lk4 + 3][lrow] = bv.w;
        __syncthreads();
        #pragma unroll
        for (int k = 0; k < 8; ++k) {
            float a[8], b[8];
            *(float4*)&a[0] = *(const float4*)&As[k][ty * 8];
            *(float4*)&a[4] = *(const float4*)&As[k][ty * 8 + 4];
            *(float4*)&b[0] = *(const float4*)&Bs[k][tx * 8];
            *(float4*)&b[4] = *(const float4*)&Bs[k][tx * 8 + 4];
            #pragma unroll
            for (int i = 0; i < 8; ++i)
                #pragma unroll
                for (int j = 0; j < 8; ++j)
                    acc[i][j] += a[i] * b[j];
        }
    }

    const int row0 = bm * 128 + ty * 8;
    const int col0 = bn * 128 + tx * 8;
    float bias[8];
    #pragma unroll
    for (int j = 0; j < 8; ++j) {
        int c = col0 + j;
        bias[j] = (c < 1024) ? b_ru[c] : b_c[c - 1024];
    }
    #pragma unroll
    for (int i = 0; i < 8; ++i) {
        float4 v0 = make_float4(acc[i][0] + bias[0], acc[i][1] + bias[1],
                                acc[i][2] + bias[2], acc[i][3] + bias[3]);
        float4 v1 = make_float4(acc[i][4] + bias[4], acc[i][5] + bias[5],
                                acc[i][6] + bias[6], acc[i][7] + bias[7]);
        float* p = pre + (size_t)(row0 + i) * NG + col0;
        *(float4*)p = v0;
        *(float4*)(p + 4) = v1;
    }
}

// ---------------- persistent cooperative recurrence ------------------------
// 256 blocks x 256 threads.  group g = bid&3 owns batches 8g..8g+7 (this
// mapping puts a group's 64 blocks on ~2 XCDs under round-robin dispatch);
// slice s = bid>>2 owns h-columns j0..j0+7 (its Wr/Wz/Wc rows live in LDS,
// loaded ONCE per launch).  thread (tid): batch = 8g + (tid>>5), lane l=tid&31
// covers k = kk*32 + l.  h and r*h cross blocks via agent-scope atomics;
// z / h_own stay in registers (column-aligned ownership).  Two flag-array
// barriers per step.
__global__ __launch_bounds__(THREADS, 1) void gru_rec(
        const float* __restrict__ W_ru, const float* __restrict__ W_c,
        const float* __restrict__ pre, float* __restrict__ h_buf,
        float* __restrict__ rh_buf, unsigned* __restrict__ flags_all,
        float* __restrict__ out, float* __restrict__ hlast,
        int t0, int Tc) {
    __shared__ float Wl[3 * JB * WSTR];      // 48.1 KB
    float* Wr_s = Wl;
    float* Wz_s = Wl + JB * WSTR;
    float* Wc_s = Wl + 2 * JB * WSTR;

    const int bid   = blockIdx.x;
    const int g     = bid & 3;               // group (XCD-affine under %8 round-robin)
    const int slice = bid >> 2;              // 0..63 within group
    const int j0    = slice * JB;
    const int tid   = threadIdx.x;
    const int b     = g * BATG + (tid >> 5); // global batch for this thread
    const int l     = tid & 31;
    const int jown  = l & 7;                 // column this lane finalizes
    unsigned* flags = flags_all + (size_t)g * BPG * FSTR;

    // one-time LDS fill: rows j0..j0+7 of Wh_r, Wh_z, Wh_c (k-contiguous)
    for (int idx = tid; idx < JB * 512; idx += THREADS) {
        int jj = idx >> 9, k = idx & 511;
        Wr_s[jj * WSTR + k] = W_ru[(size_t)(j0 + jj) * 1024 + k];
        Wz_s[jj * WSTR + k] = W_ru[(size_t)(512 + j0 + jj) * 1024 + k];
        Wc_s[jj * WSTR + k] = W_c [(size_t)(j0 + jj) * 1024 + k];
    }
    __syncthreads();

    float* hb = h_buf  + (size_t)b * Hsz;
    float* rb = rh_buf + (size_t)b * Hsz;
    unsigned bar = 0;

    for (int t = 0; t < Tc; ++t) {
        const float* prow = pre + ((size_t)t * Bsz + b) * NG;

        // ---- phase A: r,z gates for owned columns ----
        float hv[16];
        #pragma unroll
        for (int kk = 0; kk < 16; ++kk)
            hv[kk] = ld_agent(hb + kk * 32 + l);
        float h_own = ld_agent(hb + j0 + jown);

        float ar[8], az[8];
        #pragma unroll
        for (int jj = 0; jj < 8; ++jj) { ar[jj] = 0.f; az[jj] = 0.f; }
        #pragma unroll
        for (int kk = 0; kk < 16; ++kk) {
            const int k = kk * 32 + l;
            const float h = hv[kk];
            #pragma unroll
            for (int jj = 0; jj < 8; ++jj) {
                ar[jj] = fmaf(Wr_s[jj * WSTR + k], h, ar[jj]);
                az[jj] = fmaf(Wz_s[jj * WSTR + k], h, az[jj]);
            }
        }
        reduce8(ar, l);
        reduce8(az, l);

        float r = sigmoidf_(ar[0] + prow[j0 + jown]);
        float z = sigmoidf_(az[0] + prow[512 + j0 + jown]);
        if (l < 8) st_agent(rb + j0 + l, r * h_own);

        // ---- group barrier 1 (publish rh) ----
        group_barrier(flags, slice, tid, ++bar);

        // ---- phase B: candidate + h update for owned columns ----
        float rv[16];
        #pragma unroll
        for (int kk = 0; kk < 16; ++kk)
            rv[kk] = ld_agent(rb + kk * 32 + l);

        float ac[8];
        #pragma unroll
        for (int jj = 0; jj < 8; ++jj) ac[jj] = 0.f;
        #pragma unroll
        for (int kk = 0; kk < 16; ++kk) {
            const int k = kk * 32 + l;
            const float p = rv[kk];
            #pragma unroll
            for (int jj = 0; jj < 8; ++jj)
                ac[jj] = fmaf(Wc_s[jj * WSTR + k], p, ac[jj]);
        }
        reduce8(ac, l);

        float c  = tanhf_(ac[0] + prow[1024 + j0 + jown]);
        float hn = h_own + z * (c - h_own);      // (1-z)h + z*c
        if (l < 8) {
            st_agent(hb + j0 + l, hn);
            out[((size_t)b * Lsz + (t0 + t)) * Hsz + j0 + l] = hn;
            if (t0 + t == Lsz - 1) hlast[(size_t)b * Hsz + j0 + l] = hn;
        }

        // ---- group barrier 2 (publish h, protect rh from next-step WAR) ----
        group_barrier(flags, slice, tid, ++bar);
    }
}

// ---------------------------------------------------------------------------
extern "C" void kernel_launch(void* const* d_in, const int* in_sizes, int n_in,
                              void* d_out, int out_size, void* d_ws, size_t ws_size,
                              hipStream_t stream) {
    const float* x     = (const float*)d_in[0];
    const float* h0    = (const float*)d_in[1];
    const float* W_ru  = (const float*)d_in[2];
    const float* b_ru  = (const float*)d_in[3];
    const float* W_c   = (const float*)d_in[4];
    const float* b_c   = (const float*)d_in[5];
    float* out   = (float*)d_out;
    float* hlast = out + (size_t)Bsz * Lsz * Hsz;

    const int nflags = GROUPS * BPG * FSTR;     // 4096 u32 = 16 KB

    float* ws       = (float*)d_ws;
    unsigned* flags = (unsigned*)ws;
    float* h_buf    = ws + nflags;              // 32*512
    float* rh_buf   = h_buf + Bsz * Hsz;        // 32*512
    float* pre      = rh_buf + Bsz * Hsz;       // Tc*32*1536

    const size_t fixed_bytes = (size_t)(nflags + 2 * Bsz * Hsz) * 4;
    int Tc = 256;
    while (Tc > 8 && fixed_bytes + (size_t)Tc * Bsz * NG * 4 > ws_size) Tc >>= 1;

    init_h<<<(Bsz * Hsz) / 256, 256, 0, stream>>>(h0, h_buf);

    const int nchunks = Lsz / Tc;
    for (int cidx = 0; cidx < nchunks; ++cidx) {
        int t0 = cidx * Tc;
        gemm_pre<<<dim3((Tc * Bsz) / 128, NG / 128), 256, 0, stream>>>(
            x, W_ru, b_ru, W_c, b_c, pre, t0);
        hipMemsetAsync(flags, 0, nflags * sizeof(unsigned), stream);
        void* args[] = {(void*)&W_ru, (void*)&W_c, (void*)&pre, (void*)&h_buf,
                        (void*)&rh_buf, (void*)&flags, (void*)&out, (void*)&hlast,
                        (void*)&t0, (void*)&Tc};
        hipLaunchCooperativeKernel(reinterpret_cast<void*>(gru_rec),
                                   dim3(NBLK), dim3(THREADS), args, 0u, stream);
    }
}